// Round 1
// baseline (340.990 us; speedup 1.0000x reference)
//
#include <hip/hip_runtime.h>

// Problem constants (B,C,H,W)=(32,64,64,64), code_size=512
#define HWDIM 4096
#define BDIM  32
#define CDIM  64
#define KDIM  512
#define ST_ELEMS   8388608   // 32*64*64*64
#define IDX_ELEMS  131072    // 32*64*64
#define LOSS_OFF   8519680   // ST_ELEMS + IDX_ELEMS

// numpy fp32 pairwise sum-of-squares of 64 contiguous values, emulating the
// AVX-512 npyv path: r0..r3 = 4x16-lane vectors of squares, sum = (r0+r1)+(r2+r3),
// then npyv_sum_f32 tree: w[i]=v[i]+v[i+8]; x[i]=w[i]+w[i+4]; (x0+x2)+(x1+x3).
__device__ __forceinline__ float np_sumsq64(const float a[64]) {
#pragma clang fp contract(off)
  float v[16];
#pragma unroll
  for (int i = 0; i < 16; ++i) {
    float s0 = a[i]      * a[i];
    float s1 = a[i + 16] * a[i + 16];
    float s2 = a[i + 32] * a[i + 32];
    float s3 = a[i + 48] * a[i + 48];
    v[i] = (s0 + s1) + (s2 + s3);
  }
  // x[i] = (v[i]+v[i+8]) + (v[i+4]+v[i+12])
  float x0 = (v[0] + v[8])  + (v[4] + v[12]);
  float x1 = (v[1] + v[9])  + (v[5] + v[13]);
  float x2 = (v[2] + v[10]) + (v[6] + v[14]);
  float x3 = (v[3] + v[11]) + (v[7] + v[15]);
  return (x0 + x2) + (x1 + x3);
}

__global__ __launch_bounds__(256, 2) void vq_kernel(
    const float* __restrict__ x, const float* __restrict__ cb,
    float* __restrict__ st, float* __restrict__ idxo, float* __restrict__ loss)
{
  __shared__ float sc[KDIM];
  __shared__ float lred[4];

  const int tid = threadIdx.x;
  const int b   = blockIdx.x & 31;          // batch index
  const int p   = ((blockIdx.x >> 5) << 8) + tid;  // pixel index 0..4095

  // Per-block codebook sum-of-squares (identical fp32 bits in every block).
  for (int k = tid; k < KDIM; k += 256) {
    float row[64];
#pragma unroll
    for (int c = 0; c < 64; ++c) row[c] = cb[(k << 6) + c];
    sc[k] = np_sumsq64(row);
  }

  // Load this thread's point: x[b, c, p] — coalesced across lanes (consecutive p).
  float xr[64];
  const float* xp = x + (size_t)b * (CDIM * HWDIM) + p;
#pragma unroll
  for (int c = 0; c < 64; ++c) xr[c] = xp[c * HWDIM];
  const float S = np_sumsq64(xr);
  __syncthreads();

  // Argmin over 512 codes, replicating numpy fp32:
  // dist = (S - 2*dot) + sc[k]; sequential fused-FMA dot (BLAS k-order);
  // strict '<' keeps the first (lowest) index on ties, like np.argmin.
  float bestd = __builtin_inff();
  int   besti = 0;
#pragma unroll 2
  for (int k = 0; k < KDIM; ++k) {
    const float* row = cb + (k << 6);   // wave-uniform -> scalar loads
    float dot = 0.f;
#pragma unroll
    for (int c = 0; c < 64; ++c) dot = __builtin_fmaf(xr[c], row[c], dot);
    float d;
    {
#pragma clang fp contract(off)
      d = (S - (dot + dot)) + sc[k];    // 2*dot is exact; single rounding each op
    }
    if (d < bestd) { bestd = d; besti = k; }
  }

  // Gather chosen code row (per-thread contiguous 256B).
  float cr[64];
  const float* crow = cb + (besti << 6);
#pragma unroll
  for (int c = 0; c < 64; ++c) cr[c] = crow[c];

  // Loss partial: sum over c of (closest - out)^2 (tolerance is loose; any order).
  float lsum = 0.f;
#pragma unroll
  for (int c = 0; c < 64; ++c) {
    float dfc;
    {
#pragma clang fp contract(off)
      dfc = cr[c] - xr[c];
    }
    lsum = __builtin_fmaf(dfc, dfc, lsum);
  }

  // st[b, c, p] = chosen code value — coalesced stores (lane = consecutive p).
  float* stp = st + (size_t)b * (CDIM * HWDIM) + p;
#pragma unroll
  for (int c = 0; c < 64; ++c) stp[c * HWDIM] = cr[c];

  // indices[b, p] as float (d_out is one flat float32 buffer).
  idxo[b * HWDIM + p] = (float)besti;

  // Block reduce loss, one atomic per block. scale = 1.25 / (N*C) (exact pow2*5).
#pragma unroll
  for (int off = 32; off > 0; off >>= 1) lsum += __shfl_down(lsum, off);
  if ((tid & 63) == 0) lred[tid >> 6] = lsum;
  __syncthreads();
  if (tid == 0) {
    float t = (lred[0] + lred[1]) + (lred[2] + lred[3]);
    atomicAdd(loss, t * (1.25f / 8388608.f));
  }
}

extern "C" void kernel_launch(void* const* d_in, const int* in_sizes, int n_in,
                              void* d_out, int out_size, void* d_ws, size_t ws_size,
                              hipStream_t stream) {
  const float* x  = (const float*)d_in[0];   // (32,64,64,64) fp32
  const float* cb = (const float*)d_in[1];   // (512,64) fp32
  float* st   = (float*)d_out;               // (32,64,64,64)
  float* idxo = (float*)d_out + ST_ELEMS;    // (32,64,64) as float
  float* loss = (float*)d_out + LOSS_OFF;    // scalar

  hipMemsetAsync(loss, 0, sizeof(float), stream);  // d_out is poisoned each call
  vq_kernel<<<dim3(512), dim3(256), 0, stream>>>(x, cb, st, idxo, loss);
}

// Round 2
// 260.134 us; speedup vs baseline: 1.3108x; 1.3108x over previous
//
#include <hip/hip_runtime.h>

// Problem constants (B,C,H,W)=(32,64,64,64), code_size=512
#define HWDIM 4096
#define CDIM  64
#define KDIM  512
#define ST_ELEMS   8388608   // 32*64*64*64
#define LOSS_OFF   8519680   // ST_ELEMS + 32*64*64

#define REP64(M) M(0) M(1) M(2) M(3) M(4) M(5) M(6) M(7) M(8) M(9) \
  M(10) M(11) M(12) M(13) M(14) M(15) M(16) M(17) M(18) M(19) \
  M(20) M(21) M(22) M(23) M(24) M(25) M(26) M(27) M(28) M(29) \
  M(30) M(31) M(32) M(33) M(34) M(35) M(36) M(37) M(38) M(39) \
  M(40) M(41) M(42) M(43) M(44) M(45) M(46) M(47) M(48) M(49) \
  M(50) M(51) M(52) M(53) M(54) M(55) M(56) M(57) M(58) M(59) \
  M(60) M(61) M(62) M(63)

// numpy fp32 pairwise sum-of-squares of 64 contiguous values (AVX-512 npyv
// emulation), array version — used for the codebook rows (validated in R1).
__device__ __forceinline__ float np_sumsq64(const float a[64]) {
#pragma clang fp contract(off)
  float v[16];
#pragma unroll
  for (int i = 0; i < 16; ++i) {
    float s0 = a[i]      * a[i];
    float s1 = a[i + 16] * a[i + 16];
    float s2 = a[i + 32] * a[i + 32];
    float s3 = a[i + 48] * a[i + 48];
    v[i] = (s0 + s1) + (s2 + s3);
  }
  float t0 = (v[0] + v[8])  + (v[4] + v[12]);
  float t1 = (v[1] + v[9])  + (v[5] + v[13]);
  float t2 = (v[2] + v[10]) + (v[6] + v[14]);
  float t3 = (v[3] + v[11]) + (v[7] + v[15]);
  return (t0 + t2) + (t1 + t3);
}

__global__ __launch_bounds__(256, 2) void vq_kernel(
    const float* __restrict__ x, const float* __restrict__ cb,
    float* __restrict__ st, float* __restrict__ idxo, float* __restrict__ loss)
{
  __shared__ float sc[KDIM];
  __shared__ float lred[4];

  const int tid = threadIdx.x;
  const int b   = blockIdx.x & 31;                 // batch index
  const int p   = ((blockIdx.x >> 5) << 8) + tid;  // pixel index 0..4095

  // Per-block codebook sum-of-squares (identical fp32 bits in every block).
  for (int k = tid; k < KDIM; k += 256) {
    float row[64];
#pragma unroll
    for (int c = 0; c < 64; ++c) row[c] = cb[(k << 6) + c];
    sc[k] = np_sumsq64(row);
  }

  // Load this thread's point into 64 NAMED registers (array form got demoted
  // to scratch in R1: VGPR_Count=52 < 64 live values -> VALUBusy 44%).
  const float* xp = x + (size_t)b * (CDIM * HWDIM) + p;
#define XLOAD(i) float x##i = xp[(i) * HWDIM];
  REP64(XLOAD)
#undef XLOAD

  // numpy pairwise sum-of-squares of x, named-register version (same tree).
  float S;
  {
#pragma clang fp contract(off)
#define SQ(i, j, k2, l) float v##i = ((x##i * x##i) + (x##j * x##j)) + ((x##k2 * x##k2) + (x##l * x##l));
    SQ(0,16,32,48) SQ(1,17,33,49) SQ(2,18,34,50) SQ(3,19,35,51)
    SQ(4,20,36,52) SQ(5,21,37,53) SQ(6,22,38,54) SQ(7,23,39,55)
    SQ(8,24,40,56) SQ(9,25,41,57) SQ(10,26,42,58) SQ(11,27,43,59)
    SQ(12,28,44,60) SQ(13,29,45,61) SQ(14,30,46,62) SQ(15,31,47,63)
#undef SQ
    float t0 = (v0 + v8)  + (v4 + v12);
    float t1 = (v1 + v9)  + (v5 + v13);
    float t2 = (v2 + v10) + (v6 + v14);
    float t3 = (v3 + v11) + (v7 + v15);
    S = (t0 + t2) + (t1 + t3);
  }
  __syncthreads();

  // Argmin over 512 codes. Per-k dist bits identical to R1 (sequential fused
  // FMA chain in ascending c; (S - 2*dot) + sc[k]; ascending-k strict '<').
  // Unroll x4: four INDEPENDENT chains to cover FMA dep latency.
  float bestd = __builtin_inff();
  int   besti = 0;
  for (int k = 0; k < KDIM; k += 4) {
    const float* r0 = cb + (k << 6);   // wave-uniform -> scalar loads
    const float* r1 = r0 + 64;
    const float* r2 = r0 + 128;
    const float* r3 = r0 + 192;
    float d0 = 0.f, d1 = 0.f, d2 = 0.f, d3 = 0.f;
#define DOT4(i) \
    d0 = __builtin_fmaf(x##i, r0[i], d0); \
    d1 = __builtin_fmaf(x##i, r1[i], d1); \
    d2 = __builtin_fmaf(x##i, r2[i], d2); \
    d3 = __builtin_fmaf(x##i, r3[i], d3);
    REP64(DOT4)
#undef DOT4
    float e0, e1, e2, e3;
    {
#pragma clang fp contract(off)
      e0 = (S - (d0 + d0)) + sc[k];
      e1 = (S - (d1 + d1)) + sc[k + 1];
      e2 = (S - (d2 + d2)) + sc[k + 2];
      e3 = (S - (d3 + d3)) + sc[k + 3];
    }
    if (e0 < bestd) { bestd = e0; besti = k; }
    if (e1 < bestd) { bestd = e1; besti = k + 1; }
    if (e2 < bestd) { bestd = e2; besti = k + 2; }
    if (e3 < bestd) { bestd = e3; besti = k + 3; }
  }

  // Gather chosen code row, write st (coalesced: lane = consecutive p),
  // accumulate loss partial (loose tolerance; order free).
  const float* crow = cb + (besti << 6);
  float* stp = st + (size_t)b * (CDIM * HWDIM) + p;
  float lsum = 0.f;
#define EPI(i) { float cv = crow[i]; float df; \
    { _Pragma("clang fp contract(off)") df = cv - x##i; } \
    lsum = __builtin_fmaf(df, df, lsum); stp[(i) * HWDIM] = cv; }
  REP64(EPI)
#undef EPI

  // indices[b, p] as float (d_out is one flat float32 buffer).
  idxo[b * HWDIM + p] = (float)besti;

  // Block reduce loss, one atomic per block. 1.25/(N*C) is exact pow2*5.
#pragma unroll
  for (int off = 32; off > 0; off >>= 1) lsum += __shfl_down(lsum, off);
  if ((tid & 63) == 0) lred[tid >> 6] = lsum;
  __syncthreads();
  if (tid == 0) {
    float t = (lred[0] + lred[1]) + (lred[2] + lred[3]);
    atomicAdd(loss, t * (1.25f / 8388608.f));
  }
}

extern "C" void kernel_launch(void* const* d_in, const int* in_sizes, int n_in,
                              void* d_out, int out_size, void* d_ws, size_t ws_size,
                              hipStream_t stream) {
  const float* x  = (const float*)d_in[0];   // (32,64,64,64) fp32
  const float* cb = (const float*)d_in[1];   // (512,64) fp32
  float* st   = (float*)d_out;               // (32,64,64,64)
  float* idxo = (float*)d_out + ST_ELEMS;    // (32,64,64) as float
  float* loss = (float*)d_out + LOSS_OFF;    // scalar

  hipMemsetAsync(loss, 0, sizeof(float), stream);  // d_out is poisoned each call
  vq_kernel<<<dim3(512), dim3(256), 0, stream>>>(x, cb, st, idxo, loss);
}